// Round 1
// 1178.008 us; speedup vs baseline: 1.2048x; 1.2048x over previous
//
#include <hip/hip_runtime.h>
#include <hip/hip_bf16.h>
#include <cstdint>
#include <cstddef>

// out[b,o] = sum_i silu(x[b,i])*BW[o,i] + sum_{i,c} exp(-5*(x[b,i]-g_c)^2)*SW[o,i,c]
// Round 4: keep the expand-to-bf16 + GEMM decomposition, but replace the 128^2
// 2-barrier GEMM (m97-structure, ~707 TF, MfmaUtil 32%) with the 256^2 8-phase
// template: BK=64, 8 waves (2Mx4N), 128 KiB LDS (2 dbuf x {A,B} x 2 k-half slots),
// counted vmcnt(6) at phases 4/8 only, setprio(1) around each 16-MFMA cluster,
// bank-conflict-free XOR swizzle with linear global_load_lds destinations.

#define KIN 2048
#define NOUT 2048
#define BATCH 16384
#define KEXP 12288          // 2048 * 6
#define NKT 192             // KEXP / 64

typedef __bf16 bf16x8 __attribute__((ext_vector_type(8)));
typedef float f32x4 __attribute__((ext_vector_type(4)));
typedef unsigned short u16x4 __attribute__((ext_vector_type(4)));

__device__ __forceinline__ unsigned short f2bf(float f) {
    union { float f; uint32_t u; } v; v.f = f;
    return (unsigned short)((v.u + 0x7FFFu + ((v.u >> 16) & 1u)) >> 16);
}

__device__ __forceinline__ void load_lds16(const void* gptr, void* lptr) {
    __builtin_amdgcn_global_load_lds(
        (const __attribute__((address_space(1))) unsigned int*)gptr,
        (__attribute__((address_space(3))) unsigned int*)lptr,
        16, 0, 0);
}

// ---------------- expansion: x -> Aexp (bf16, k = i*6 + j) ----------------
__global__ __launch_bounds__(256)
void expand_a(const float* __restrict__ X, __bf16* __restrict__ Aexp)
{
    const int idx = blockIdx.x * 256 + threadIdx.x;   // 16384 * 512
    const int row = idx >> 9;
    const int g   = idx & 511;                        // 4-feature group
    const f32x4 xv = *(const f32x4*)(X + (size_t)row * KIN + g * 4);
    __bf16 o[24];
    #pragma unroll
    for (int e = 0; e < 4; ++e) {
        const float xf = xv[e];
        #pragma unroll
        for (int c = 0; c < 5; ++c) {
            const float d = xf - (-1.0f + 0.5f * (float)c);
            o[e * 6 + c] = (__bf16)__expf(-5.0f * d * d);
        }
        o[e * 6 + 5] = (__bf16)(xf / (1.0f + __expf(-xf)));
    }
    __bf16* dst = Aexp + (size_t)row * KEXP + g * 24;
    #pragma unroll
    for (int q = 0; q < 3; ++q) {
        bf16x8 v;
        #pragma unroll
        for (int t = 0; t < 8; ++t) v[t] = o[q * 8 + t];
        *(bf16x8*)(dst + q * 8) = v;
    }
}

// ---------------- expansion: BW/SW -> Wexp (bf16, same k order) ----------------
__global__ __launch_bounds__(256)
void expand_w(const float* __restrict__ BW, const float* __restrict__ SW,
              __bf16* __restrict__ Wexp)
{
    const int idx = blockIdx.x * 256 + threadIdx.x;   // 2048 * 512
    const int orow = idx >> 9;
    const int g    = idx & 511;
    const int i0   = g * 4;
    const float* sb = SW + ((size_t)orow * KIN + i0) * 5;   // 20 contiguous floats
    const f32x4 bw = *(const f32x4*)(BW + (size_t)orow * KIN + i0);
    float sw[20];
    #pragma unroll
    for (int q = 0; q < 5; ++q) {
        const f32x4 v = *(const f32x4*)(sb + q * 4);
        sw[q * 4 + 0] = v.x; sw[q * 4 + 1] = v.y; sw[q * 4 + 2] = v.z; sw[q * 4 + 3] = v.w;
    }
    __bf16 o[24];
    #pragma unroll
    for (int e = 0; e < 4; ++e) {
        #pragma unroll
        for (int c = 0; c < 5; ++c) o[e * 6 + c] = (__bf16)sw[e * 5 + c];
        o[e * 6 + 5] = (__bf16)bw[e];
    }
    __bf16* dst = Wexp + (size_t)orow * KEXP + g * 24;
    #pragma unroll
    for (int q = 0; q < 3; ++q) {
        bf16x8 v;
        #pragma unroll
        for (int t = 0; t < 8; ++t) v[t] = o[q * 8 + t];
        *(bf16x8*)(dst + q * 8) = v;
    }
}

// ---------------- 256x256 8-phase GEMM: OUT[16384][2048] = Aexp * Wexp^T --------
// Per iteration: 2 K-tiles (BK=64 each), 8 phases. Phase = {ds_read subtile,
// stage 1 k-half slot (2 x global_load_lds 16B), s_barrier, setprio(1), 16 MFMA,
// setprio(0), s_barrier}. vmcnt(6) only at phases 4 and 8.
//
// LDS layout per matrix: [2 dbuf][2 k-half][256 rows][4 chunks of 8 bf16].
// Swizzle: physical chunk p = logical chunk j ^ ((row>>1)&3). With the row-parity
// bank offset this gives exactly 2 rows per 16B bank-slot per wave64 ds_read_b128
// (conflict-free minimum). Staging dest is linear (global_load_lds requirement);
// the inverse permutation is applied to the per-lane GLOBAL source address.
//
// vmcnt ledger (per wave, 2 loads per stage):
//   steady-state leftovers entering p1 = {p6,p7,p8 of prev iter} = 6 loads.
//   p1..p4 stage +8 -> 14 -> vmcnt(6) completes through p1 (A[buf1,khi] needed p7).
//   p5..p8 stage +8 -> 14 -> vmcnt(6) completes through p5 (buf0 next K-tile,
//   needed at next iter p1..p4). Slot staged at phase p is last-read at p-1
//   (issue happens after p-1's closing barrier -> write-after-read safe).
__global__ __launch_bounds__(512, 2)
void gemm8(const __bf16* __restrict__ A, const __bf16* __restrict__ W,
           float* __restrict__ OUT)
{
    __shared__ __align__(16) __bf16 LDS[65536];   // 128 KiB
    __bf16* LA = LDS;              // [2buf][2kh][8192 elems]
    __bf16* LB = LDS + 32768;

    const int tid  = threadIdx.x;
    const int lane = tid & 63;
    const int wave = tid >> 6;     // 0..7
    const int r    = lane & 15;
    const int quad = lane >> 4;
    const int wm   = wave >> 2;    // 0..1  (M)
    const int wn   = wave & 3;     // 0..3  (N)

    const int bid = blockIdx.x;    // 512 blocks
    const int mt  = bid >> 3;      // 64 m-tiles
    const int nt  = bid & 7;       // 8 n-tiles
    const int m0  = mt * 256;
    const int n0  = nt * 256;

    // ---- staging source addresses (per-lane, pre-swizzled) ----
    const int c0   = tid;                          // slot chunk ids 0..511
    const int c1   = tid + 512;                    // 512..1023
    const int row0 = c0 >> 2, row1 = c1 >> 2;      // slot rows 0..255
    const int j0   = (c0 & 3) ^ ((c0 >> 3) & 3);   // logical chunk for phys slot
    const int j1   = (c1 & 3) ^ ((c1 >> 3) & 3);
    const __bf16* srcA0 = A + (size_t)(m0 + row0) * KEXP + j0 * 8;
    const __bf16* srcA1 = A + (size_t)(m0 + row1) * KEXP + j1 * 8;
    const __bf16* srcB0 = W + (size_t)(n0 + row0) * KEXP + j0 * 8;
    const __bf16* srcB1 = W + (size_t)(n0 + row1) * KEXP + j1 * 8;

    // LDS stage destinations: wave-uniform base; HW adds lane*16B.
    const int dst0 = wave * 512;          // issue s=0 (elems)
    const int dst1 = 4096 + wave * 512;   // issue s=1

    // ---- fragment read bases (swizzled) ----
    const int swz = (quad ^ ((r >> 1) & 3)) * 8;
    const __bf16* a_rd = LA + (wm * 128 + r) * 32 + swz;
    const __bf16* b_rd = LB + (wn * 64 + r) * 32 + swz;

    f32x4 acc[8][4];
    #pragma unroll
    for (int i = 0; i < 8; ++i)
        #pragma unroll
        for (int j = 0; j < 4; ++j)
            acc[i][j] = (f32x4){0.0f, 0.0f, 0.0f, 0.0f};

    bf16x8 af[4], bf[4];

#define BARX() asm volatile("s_barrier" ::: "memory")
#define VM6()  asm volatile("s_waitcnt vmcnt(6)" ::: "memory")

#define STAGE_A(buf, kh, kt) do { \
    const size_t ko = (size_t)(kt) * 64 + (kh) * 32; \
    load_lds16(srcA0 + ko, LA + ((buf) * 2 + (kh)) * 8192 + dst0); \
    load_lds16(srcA1 + ko, LA + ((buf) * 2 + (kh)) * 8192 + dst1); } while (0)

#define STAGE_B(buf, kh, kt) do { \
    const size_t ko = (size_t)(kt) * 64 + (kh) * 32; \
    load_lds16(srcB0 + ko, LB + ((buf) * 2 + (kh)) * 8192 + dst0); \
    load_lds16(srcB1 + ko, LB + ((buf) * 2 + (kh)) * 8192 + dst1); } while (0)

#define READ_A(buf, ks, a) do { \
    const __bf16* p_ = a_rd + ((buf) * 2 + (ks)) * 8192 + (a) * 2048; \
    af[0] = *(const bf16x8*)(p_); \
    af[1] = *(const bf16x8*)(p_ + 512); \
    af[2] = *(const bf16x8*)(p_ + 1024); \
    af[3] = *(const bf16x8*)(p_ + 1536); } while (0)

#define READ_B(buf, ks) do { \
    const __bf16* p_ = b_rd + ((buf) * 2 + (ks)) * 8192; \
    bf[0] = *(const bf16x8*)(p_); \
    bf[1] = *(const bf16x8*)(p_ + 512); \
    bf[2] = *(const bf16x8*)(p_ + 1024); \
    bf[3] = *(const bf16x8*)(p_ + 1536); } while (0)

#define MFMA_Q(a) do { \
    __builtin_amdgcn_s_setprio(1); \
    _Pragma("unroll") \
    for (int mi_ = 0; mi_ < 4; ++mi_) { \
        _Pragma("unroll") \
        for (int nj_ = 0; nj_ < 4; ++nj_) \
            acc[(a) * 4 + mi_][nj_] = __builtin_amdgcn_mfma_f32_16x16x32_bf16( \
                af[mi_], bf[nj_], acc[(a) * 4 + mi_][nj_], 0, 0, 0); \
    } \
    __builtin_amdgcn_s_setprio(0); } while (0)

    // ---- prologue: K-tile 0 full (buf0) + 3 of K-tile 1 (buf1) = 14 loads ----
    STAGE_B(0, 0, 0); STAGE_A(0, 0, 0); STAGE_B(0, 1, 0); STAGE_A(0, 1, 0);
    STAGE_B(1, 0, 1); STAGE_A(1, 0, 1); STAGE_B(1, 1, 1);
    VM6();            // completes the 4 buf0 slots; leaves buf1's 3 in flight
    BARX();

    // ---- main loop: 96 iterations x 2 K-tiles ----
    for (int t = 0; t < 96; ++t) {
        const int kt1 = 2 * t + 1;
        const int sA  = (2 * t + 2 < NKT) ? 2 * t + 2 : NKT - 1;  // clamp: staged-
        const int sB  = (2 * t + 3 < NKT) ? 2 * t + 3 : NKT - 1;  // never-read tail
        // p1: quad (a=0, ks=0) of buf0; stage A[buf1,khi] <- kt1 (needed p7/p8)
        READ_A(0, 0, 0); READ_B(0, 0);
        STAGE_A(1, 1, kt1);
        BARX(); MFMA_Q(0); BARX();
        // p2: (a=1, ks=0), B ks0 reused from regs; stage B[buf0,klo] <- kt+2
        READ_A(0, 0, 1);
        STAGE_B(0, 0, sA);
        BARX(); MFMA_Q(1); BARX();
        // p3: (a=1, ks=1); stage A[buf0,klo]
        READ_A(0, 1, 1); READ_B(0, 1);
        STAGE_A(0, 0, sA);
        BARX(); MFMA_Q(1); BARX();
        // p4: (a=0, ks=1); stage B[buf0,khi]; counted vmcnt
        READ_A(0, 1, 0);
        STAGE_B(0, 1, sA);
        VM6();
        BARX(); MFMA_Q(0); BARX();
        // p5: buf1 (a=0, ks=0); stage A[buf0,khi]
        READ_A(1, 0, 0); READ_B(1, 0);
        STAGE_A(0, 1, sA);
        BARX(); MFMA_Q(0); BARX();
        // p6: (a=1, ks=0); stage B[buf1,klo] <- kt+3
        READ_A(1, 0, 1);
        STAGE_B(1, 0, sB);
        BARX(); MFMA_Q(1); BARX();
        // p7: (a=1, ks=1); stage A[buf1,klo]
        READ_A(1, 1, 1); READ_B(1, 1);
        STAGE_A(1, 0, sB);
        BARX(); MFMA_Q(1); BARX();
        // p8: (a=0, ks=1); stage B[buf1,khi]; counted vmcnt
        READ_A(1, 1, 0);
        STAGE_B(1, 1, sB);
        VM6();
        BARX(); MFMA_Q(0); BARX();
    }

    // ---- epilogue: C/D layout col = lane&15, row = quad*4 + reg ----
    #pragma unroll
    for (int fi = 0; fi < 8; ++fi) {
        #pragma unroll
        for (int nj = 0; nj < 4; ++nj) {
            const int col  = n0 + wn * 64 + nj * 16 + r;
            const int rowb = m0 + wm * 128 + fi * 16 + quad * 4;
            #pragma unroll
            for (int reg = 0; reg < 4; ++reg)
                OUT[(size_t)(rowb + reg) * NOUT + col] = acc[fi][nj][reg];
        }
    }
#undef BARX
#undef VM6
#undef STAGE_A
#undef STAGE_B
#undef READ_A
#undef READ_B
#undef MFMA_Q
}

// ---------------- fallback: validated round-2 fused kernel ----------------
#define BM 128
#define BN 128
#define NF 16
#define BK 96
#define LDK 104

__global__ __launch_bounds__(256)
void kan_fused(const float* __restrict__ X, const float* __restrict__ BW,
               const float* __restrict__ SW, float* __restrict__ OUT)
{
    __shared__ __align__(16) unsigned short As[BM * LDK];
    __shared__ __align__(16) unsigned short Bs[BN * LDK];

    const int tid  = threadIdx.x;
    const int lane = tid & 63;
    const int wave = tid >> 6;
    const int mt = blockIdx.x >> 4;
    const int nt = blockIdx.x & 15;
    const int m0 = mt * BM;
    const int n0 = nt * BN;
    const int r    = lane & 15;
    const int quad = lane >> 4;
    const int wm = (wave & 1) * 64;
    const int wn = (wave >> 1) * 64;

    f32x4 acc[4][4];
    #pragma unroll
    for (int i = 0; i < 4; ++i)
        #pragma unroll
        for (int j = 0; j < 4; ++j)
            acc[i][j] = (f32x4){0.0f, 0.0f, 0.0f, 0.0f};

    for (int it = 0; it < KIN / NF; ++it) {
        const int i0 = it * NF;
        __syncthreads();
        #pragma unroll
        for (int s = 0; s < 2; ++s) {
            const int slot = tid + s * 256;
            const int row  = slot >> 2;
            const int fq   = slot & 3;
            const f32x4 xv = *(const f32x4*)(X + (size_t)(m0 + row) * KIN + i0 + fq * 4);
            unsigned short basv[20];
            unsigned short silv[4];
            #pragma unroll
            for (int e = 0; e < 4; ++e) {
                const float xf = xv[e];
                silv[e] = f2bf(xf / (1.0f + __expf(-xf)));
                #pragma unroll
                for (int c = 0; c < 5; ++c) {
                    const float d = xf - (-1.0f + 0.5f * (float)c);
                    basv[e * 5 + c] = f2bf(__expf(-5.0f * d * d));
                }
            }
            unsigned short* dst = As + row * LDK + fq * 20;
            #pragma unroll
            for (int q = 0; q < 5; ++q) {
                u16x4 v;
                v.x = basv[q * 4 + 0]; v.y = basv[q * 4 + 1];
                v.z = basv[q * 4 + 2]; v.w = basv[q * 4 + 3];
                *(u16x4*)(dst + q * 4) = v;
            }
            u16x4 sv;
            sv.x = silv[0]; sv.y = silv[1]; sv.z = silv[2]; sv.w = silv[3];
            *(u16x4*)(As + row * LDK + 80 + fq * 4) = sv;
        }
        {
            const int orow = tid >> 1;
            const int half = tid & 1;
            const float* sbase = SW + (size_t)(n0 + orow) * (KIN * 5) + i0 * 5 + half * 40;
            unsigned short* brow = Bs + orow * LDK + half * 40;
            #pragma unroll
            for (int p = 0; p < 10; ++p) {
                const f32x4 wv = *(const f32x4*)(sbase + p * 4);
                u16x4 v;
                v.x = f2bf(wv.x); v.y = f2bf(wv.y);
                v.z = f2bf(wv.z); v.w = f2bf(wv.w);
                *(u16x4*)(brow + p * 4) = v;
            }
        }
        #pragma unroll
        for (int s = 0; s < 2; ++s) {
            const int slot = tid + s * 256;
            const int row  = slot >> 2;
            const int fq   = slot & 3;
            const f32x4 wv = *(const f32x4*)(BW + (size_t)(n0 + row) * KIN + i0 + fq * 4);
            u16x4 v;
            v.x = f2bf(wv.x); v.y = f2bf(wv.y);
            v.z = f2bf(wv.z); v.w = f2bf(wv.w);
            *(u16x4*)(Bs + row * LDK + 80 + fq * 4) = v;
        }
        __syncthreads();
        #pragma unroll
        for (int ks = 0; ks < 3; ++ks) {
            bf16x8 af[4], bfr[4];
            #pragma unroll
            for (int mi = 0; mi < 4; ++mi)
                af[mi] = *(const bf16x8*)(As + (wm + mi * 16 + r) * LDK + ks * 32 + quad * 8);
            #pragma unroll
            for (int ni = 0; ni < 4; ++ni)
                bfr[ni] = *(const bf16x8*)(Bs + (wn + ni * 16 + r) * LDK + ks * 32 + quad * 8);
            #pragma unroll
            for (int mi = 0; mi < 4; ++mi)
                #pragma unroll
                for (int ni = 0; ni < 4; ++ni)
                    acc[mi][ni] = __builtin_amdgcn_mfma_f32_16x16x32_bf16(
                        af[mi], bfr[ni], acc[mi][ni], 0, 0, 0);
        }
    }
    #pragma unroll
    for (int mi = 0; mi < 4; ++mi) {
        #pragma unroll
        for (int ni = 0; ni < 4; ++ni) {
            const int col  = n0 + wn + ni * 16 + r;
            const int rowb = m0 + wm + mi * 16 + quad * 4;
            #pragma unroll
            for (int reg = 0; reg < 4; ++reg)
                OUT[(size_t)(rowb + reg) * NOUT + col] = acc[mi][ni][reg];
        }
    }
}

extern "C" void kernel_launch(void* const* d_in, const int* in_sizes, int n_in,
                              void* d_out, int out_size, void* d_ws, size_t ws_size,
                              hipStream_t stream) {
    const float* X  = (const float*)d_in[0];
    const float* BW = (const float*)d_in[1];
    const float* SW = (const float*)d_in[2];
    float* OUT = (float*)d_out;

    const size_t nA = (size_t)BATCH * KEXP;          // 201,326,592 elems
    const size_t nW = (size_t)NOUT * KEXP;           //  25,165,824 elems
    const size_t ws_need = (nA + nW) * sizeof(__bf16);   // 452,984,832 B

    if (ws_size >= ws_need) {
        __bf16* Aexp = (__bf16*)d_ws;
        __bf16* Wexp = Aexp + nA;
        expand_a<<<dim3(BATCH * 512 / 256), dim3(256), 0, stream>>>(X, Aexp);
        expand_w<<<dim3(NOUT * 512 / 256), dim3(256), 0, stream>>>(BW, SW, Wexp);
        gemm8<<<dim3(512), dim3(512), 0, stream>>>(Aexp, Wexp, OUT);
    } else {
        kan_fused<<<dim3(128 * 16), dim3(256), 0, stream>>>(X, BW, SW, OUT);
    }
}

// Round 2
// 995.774 us; speedup vs baseline: 1.4253x; 1.1830x over previous
//
#include <hip/hip_runtime.h>
#include <hip/hip_bf16.h>
#include <cstdint>
#include <cstddef>

// out[b,o] = sum_i silu(x[b,i])*BW[o,i] + sum_{i,c} exp(-5*(x[b,i]-g_c)^2)*SW[o,i,c]
// Round 5: round-4's 256^2 8-phase GEMM (976 TF, MfmaUtil 46%) + T1 XCD-aware
// bijective blockIdx swizzle. rocprof showed FETCH_SIZE = 2.37 GB vs 453 MB
// minimum (5.2x A re-fetch: bid%8 = nt means every A panel is pulled by all 8
// XCDs). Chunked remap gives each XCD 8 consecutive m-tiles x all n-tiles ->
// per-K-step working set 384 KB, L2-resident; A fetched ~once.

#define KIN 2048
#define NOUT 2048
#define BATCH 16384
#define KEXP 12288          // 2048 * 6
#define NKT 192             // KEXP / 64

typedef __bf16 bf16x8 __attribute__((ext_vector_type(8)));
typedef float f32x4 __attribute__((ext_vector_type(4)));
typedef unsigned short u16x4 __attribute__((ext_vector_type(4)));

__device__ __forceinline__ unsigned short f2bf(float f) {
    union { float f; uint32_t u; } v; v.f = f;
    return (unsigned short)((v.u + 0x7FFFu + ((v.u >> 16) & 1u)) >> 16);
}

__device__ __forceinline__ void load_lds16(const void* gptr, void* lptr) {
    __builtin_amdgcn_global_load_lds(
        (const __attribute__((address_space(1))) unsigned int*)gptr,
        (__attribute__((address_space(3))) unsigned int*)lptr,
        16, 0, 0);
}

// ---------------- expansion: x -> Aexp (bf16, k = i*6 + j) ----------------
__global__ __launch_bounds__(256)
void expand_a(const float* __restrict__ X, __bf16* __restrict__ Aexp)
{
    const int idx = blockIdx.x * 256 + threadIdx.x;   // 16384 * 512
    const int row = idx >> 9;
    const int g   = idx & 511;                        // 4-feature group
    const f32x4 xv = *(const f32x4*)(X + (size_t)row * KIN + g * 4);
    __bf16 o[24];
    #pragma unroll
    for (int e = 0; e < 4; ++e) {
        const float xf = xv[e];
        #pragma unroll
        for (int c = 0; c < 5; ++c) {
            const float d = xf - (-1.0f + 0.5f * (float)c);
            o[e * 6 + c] = (__bf16)__expf(-5.0f * d * d);
        }
        o[e * 6 + 5] = (__bf16)(xf / (1.0f + __expf(-xf)));
    }
    __bf16* dst = Aexp + (size_t)row * KEXP + g * 24;
    #pragma unroll
    for (int q = 0; q < 3; ++q) {
        bf16x8 v;
        #pragma unroll
        for (int t = 0; t < 8; ++t) v[t] = o[q * 8 + t];
        *(bf16x8*)(dst + q * 8) = v;
    }
}

// ---------------- expansion: BW/SW -> Wexp (bf16, same k order) ----------------
__global__ __launch_bounds__(256)
void expand_w(const float* __restrict__ BW, const float* __restrict__ SW,
              __bf16* __restrict__ Wexp)
{
    const int idx = blockIdx.x * 256 + threadIdx.x;   // 2048 * 512
    const int orow = idx >> 9;
    const int g    = idx & 511;
    const int i0   = g * 4;
    const float* sb = SW + ((size_t)orow * KIN + i0) * 5;   // 20 contiguous floats
    const f32x4 bw = *(const f32x4*)(BW + (size_t)orow * KIN + i0);
    float sw[20];
    #pragma unroll
    for (int q = 0; q < 5; ++q) {
        const f32x4 v = *(const f32x4*)(sb + q * 4);
        sw[q * 4 + 0] = v.x; sw[q * 4 + 1] = v.y; sw[q * 4 + 2] = v.z; sw[q * 4 + 3] = v.w;
    }
    __bf16 o[24];
    #pragma unroll
    for (int e = 0; e < 4; ++e) {
        #pragma unroll
        for (int c = 0; c < 5; ++c) o[e * 6 + c] = (__bf16)sw[e * 5 + c];
        o[e * 6 + 5] = (__bf16)bw[e];
    }
    __bf16* dst = Wexp + (size_t)orow * KEXP + g * 24;
    #pragma unroll
    for (int q = 0; q < 3; ++q) {
        bf16x8 v;
        #pragma unroll
        for (int t = 0; t < 8; ++t) v[t] = o[q * 8 + t];
        *(bf16x8*)(dst + q * 8) = v;
    }
}

// ---------------- 256x256 8-phase GEMM: OUT[16384][2048] = Aexp * Wexp^T --------
// Per iteration: 2 K-tiles (BK=64 each), 8 phases. Phase = {ds_read subtile,
// stage 1 k-half slot (2 x global_load_lds 16B), s_barrier, setprio(1), 16 MFMA,
// setprio(0), s_barrier}. vmcnt(6) only at phases 4 and 8.
//
// T1: blockIdx remapped (bid%8 = XCD under round-robin dispatch) so XCD k owns
// m-tiles [8k, 8k+8) x all 8 n-tiles. 512 % 8 == 0 -> simple form is bijective.
//
// LDS layout per matrix: [2 dbuf][2 k-half][256 rows][4 chunks of 8 bf16].
// Swizzle: physical chunk p = logical chunk j ^ ((row>>1)&3); staging dest is
// linear (global_load_lds requirement), inverse permutation applied to the
// per-lane GLOBAL source address. Measured SQ_LDS_BANK_CONFLICT = 0.
//
// vmcnt ledger (per wave, 2 loads per stage):
//   steady-state leftovers entering p1 = {p6,p7,p8 of prev iter} = 6 loads.
//   p1..p4 stage +8 -> 14 -> vmcnt(6) completes through p1 (A[buf1,khi] needed p7).
//   p5..p8 stage +8 -> 14 -> vmcnt(6) completes through p5 (buf0 next K-tile,
//   needed at next iter p1..p4). Slot staged at phase p is last-read at p-1
//   (issue happens after p-1's closing barrier -> write-after-read safe).
__global__ __launch_bounds__(512, 2)
void gemm8(const __bf16* __restrict__ A, const __bf16* __restrict__ W,
           float* __restrict__ OUT)
{
    __shared__ __align__(16) __bf16 LDS[65536];   // 128 KiB
    __bf16* LA = LDS;              // [2buf][2kh][8192 elems]
    __bf16* LB = LDS + 32768;

    const int tid  = threadIdx.x;
    const int lane = tid & 63;
    const int wave = tid >> 6;     // 0..7
    const int r    = lane & 15;
    const int quad = lane >> 4;
    const int wm   = wave >> 2;    // 0..1  (M)
    const int wn   = wave & 3;     // 0..3  (N)

    // T1 XCD-aware bijective swizzle: 512 blocks, 8 XCDs, chunk = 64.
    const int bid0 = blockIdx.x;
    const int bid  = (bid0 & 7) * 64 + (bid0 >> 3);
    const int mt  = bid >> 3;      // 64 m-tiles
    const int nt  = bid & 7;       // 8 n-tiles
    const int m0  = mt * 256;
    const int n0  = nt * 256;

    // ---- staging source addresses (per-lane, pre-swizzled) ----
    const int c0   = tid;                          // slot chunk ids 0..511
    const int c1   = tid + 512;                    // 512..1023
    const int row0 = c0 >> 2, row1 = c1 >> 2;      // slot rows 0..255
    const int j0   = (c0 & 3) ^ ((c0 >> 3) & 3);   // logical chunk for phys slot
    const int j1   = (c1 & 3) ^ ((c1 >> 3) & 3);
    const __bf16* srcA0 = A + (size_t)(m0 + row0) * KEXP + j0 * 8;
    const __bf16* srcA1 = A + (size_t)(m0 + row1) * KEXP + j1 * 8;
    const __bf16* srcB0 = W + (size_t)(n0 + row0) * KEXP + j0 * 8;
    const __bf16* srcB1 = W + (size_t)(n0 + row1) * KEXP + j1 * 8;

    // LDS stage destinations: wave-uniform base; HW adds lane*16B.
    const int dst0 = wave * 512;          // issue s=0 (elems)
    const int dst1 = 4096 + wave * 512;   // issue s=1

    // ---- fragment read bases (swizzled) ----
    const int swz = (quad ^ ((r >> 1) & 3)) * 8;
    const __bf16* a_rd = LA + (wm * 128 + r) * 32 + swz;
    const __bf16* b_rd = LB + (wn * 64 + r) * 32 + swz;

    f32x4 acc[8][4];
    #pragma unroll
    for (int i = 0; i < 8; ++i)
        #pragma unroll
        for (int j = 0; j < 4; ++j)
            acc[i][j] = (f32x4){0.0f, 0.0f, 0.0f, 0.0f};

    bf16x8 af[4], bf[4];

#define BARX() asm volatile("s_barrier" ::: "memory")
#define VM6()  asm volatile("s_waitcnt vmcnt(6)" ::: "memory")

#define STAGE_A(buf, kh, kt) do { \
    const size_t ko = (size_t)(kt) * 64 + (kh) * 32; \
    load_lds16(srcA0 + ko, LA + ((buf) * 2 + (kh)) * 8192 + dst0); \
    load_lds16(srcA1 + ko, LA + ((buf) * 2 + (kh)) * 8192 + dst1); } while (0)

#define STAGE_B(buf, kh, kt) do { \
    const size_t ko = (size_t)(kt) * 64 + (kh) * 32; \
    load_lds16(srcB0 + ko, LB + ((buf) * 2 + (kh)) * 8192 + dst0); \
    load_lds16(srcB1 + ko, LB + ((buf) * 2 + (kh)) * 8192 + dst1); } while (0)

#define READ_A(buf, ks, a) do { \
    const __bf16* p_ = a_rd + ((buf) * 2 + (ks)) * 8192 + (a) * 2048; \
    af[0] = *(const bf16x8*)(p_); \
    af[1] = *(const bf16x8*)(p_ + 512); \
    af[2] = *(const bf16x8*)(p_ + 1024); \
    af[3] = *(const bf16x8*)(p_ + 1536); } while (0)

#define READ_B(buf, ks) do { \
    const __bf16* p_ = b_rd + ((buf) * 2 + (ks)) * 8192; \
    bf[0] = *(const bf16x8*)(p_); \
    bf[1] = *(const bf16x8*)(p_ + 512); \
    bf[2] = *(const bf16x8*)(p_ + 1024); \
    bf[3] = *(const bf16x8*)(p_ + 1536); } while (0)

#define MFMA_Q(a) do { \
    __builtin_amdgcn_s_setprio(1); \
    _Pragma("unroll") \
    for (int mi_ = 0; mi_ < 4; ++mi_) { \
        _Pragma("unroll") \
        for (int nj_ = 0; nj_ < 4; ++nj_) \
            acc[(a) * 4 + mi_][nj_] = __builtin_amdgcn_mfma_f32_16x16x32_bf16( \
                af[mi_], bf[nj_], acc[(a) * 4 + mi_][nj_], 0, 0, 0); \
    } \
    __builtin_amdgcn_s_setprio(0); } while (0)

    // ---- prologue: K-tile 0 full (buf0) + 3 of K-tile 1 (buf1) = 14 loads ----
    STAGE_B(0, 0, 0); STAGE_A(0, 0, 0); STAGE_B(0, 1, 0); STAGE_A(0, 1, 0);
    STAGE_B(1, 0, 1); STAGE_A(1, 0, 1); STAGE_B(1, 1, 1);
    VM6();            // completes the 4 buf0 slots; leaves buf1's 3 in flight
    BARX();

    // ---- main loop: 96 iterations x 2 K-tiles ----
    for (int t = 0; t < 96; ++t) {
        const int kt1 = 2 * t + 1;
        const int sA  = (2 * t + 2 < NKT) ? 2 * t + 2 : NKT - 1;  // clamp: staged-
        const int sB  = (2 * t + 3 < NKT) ? 2 * t + 3 : NKT - 1;  // never-read tail
        // p1: quad (a=0, ks=0) of buf0; stage A[buf1,khi] <- kt1 (needed p7/p8)
        READ_A(0, 0, 0); READ_B(0, 0);
        STAGE_A(1, 1, kt1);
        BARX(); MFMA_Q(0); BARX();
        // p2: (a=1, ks=0), B ks0 reused from regs; stage B[buf0,klo] <- kt+2
        READ_A(0, 0, 1);
        STAGE_B(0, 0, sA);
        BARX(); MFMA_Q(1); BARX();
        // p3: (a=1, ks=1); stage A[buf0,klo]
        READ_A(0, 1, 1); READ_B(0, 1);
        STAGE_A(0, 0, sA);
        BARX(); MFMA_Q(1); BARX();
        // p4: (a=0, ks=1); stage B[buf0,khi]; counted vmcnt
        READ_A(0, 1, 0);
        STAGE_B(0, 1, sA);
        VM6();
        BARX(); MFMA_Q(0); BARX();
        // p5: buf1 (a=0, ks=0); stage A[buf0,khi]
        READ_A(1, 0, 0); READ_B(1, 0);
        STAGE_A(0, 1, sA);
        BARX(); MFMA_Q(0); BARX();
        // p6: (a=1, ks=0); stage B[buf1,klo] <- kt+3
        READ_A(1, 0, 1);
        STAGE_B(1, 0, sB);
        BARX(); MFMA_Q(1); BARX();
        // p7: (a=1, ks=1); stage A[buf1,klo]
        READ_A(1, 1, 1); READ_B(1, 1);
        STAGE_A(1, 0, sB);
        BARX(); MFMA_Q(1); BARX();
        // p8: (a=0, ks=1); stage B[buf1,khi]; counted vmcnt
        READ_A(1, 1, 0);
        STAGE_B(1, 1, sB);
        VM6();
        BARX(); MFMA_Q(0); BARX();
    }

    // ---- epilogue: C/D layout col = lane&15, row = quad*4 + reg ----
    #pragma unroll
    for (int fi = 0; fi < 8; ++fi) {
        #pragma unroll
        for (int nj = 0; nj < 4; ++nj) {
            const int col  = n0 + wn * 64 + nj * 16 + r;
            const int rowb = m0 + wm * 128 + fi * 16 + quad * 4;
            #pragma unroll
            for (int reg = 0; reg < 4; ++reg)
                OUT[(size_t)(rowb + reg) * NOUT + col] = acc[fi][nj][reg];
        }
    }
#undef BARX
#undef VM6
#undef STAGE_A
#undef STAGE_B
#undef READ_A
#undef READ_B
#undef MFMA_Q
}

// ---------------- fallback: validated round-2 fused kernel ----------------
#define BM 128
#define BN 128
#define NF 16
#define BK 96
#define LDK 104

__global__ __launch_bounds__(256)
void kan_fused(const float* __restrict__ X, const float* __restrict__ BW,
               const float* __restrict__ SW, float* __restrict__ OUT)
{
    __shared__ __align__(16) unsigned short As[BM * LDK];
    __shared__ __align__(16) unsigned short Bs[BN * LDK];

    const int tid  = threadIdx.x;
    const int lane = tid & 63;
    const int wave = tid >> 6;
    const int mt = blockIdx.x >> 4;
    const int nt = blockIdx.x & 15;
    const int m0 = mt * BM;
    const int n0 = nt * BN;
    const int r    = lane & 15;
    const int quad = lane >> 4;
    const int wm = (wave & 1) * 64;
    const int wn = (wave >> 1) * 64;

    f32x4 acc[4][4];
    #pragma unroll
    for (int i = 0; i < 4; ++i)
        #pragma unroll
        for (int j = 0; j < 4; ++j)
            acc[i][j] = (f32x4){0.0f, 0.0f, 0.0f, 0.0f};

    for (int it = 0; it < KIN / NF; ++it) {
        const int i0 = it * NF;
        __syncthreads();
        #pragma unroll
        for (int s = 0; s < 2; ++s) {
            const int slot = tid + s * 256;
            const int row  = slot >> 2;
            const int fq   = slot & 3;
            const f32x4 xv = *(const f32x4*)(X + (size_t)(m0 + row) * KIN + i0 + fq * 4);
            unsigned short basv[20];
            unsigned short silv[4];
            #pragma unroll
            for (int e = 0; e < 4; ++e) {
                const float xf = xv[e];
                silv[e] = f2bf(xf / (1.0f + __expf(-xf)));
                #pragma unroll
                for (int c = 0; c < 5; ++c) {
                    const float d = xf - (-1.0f + 0.5f * (float)c);
                    basv[e * 5 + c] = f2bf(__expf(-5.0f * d * d));
                }
            }
            unsigned short* dst = As + row * LDK + fq * 20;
            #pragma unroll
            for (int q = 0; q < 5; ++q) {
                u16x4 v;
                v.x = basv[q * 4 + 0]; v.y = basv[q * 4 + 1];
                v.z = basv[q * 4 + 2]; v.w = basv[q * 4 + 3];
                *(u16x4*)(dst + q * 4) = v;
            }
            u16x4 sv;
            sv.x = silv[0]; sv.y = silv[1]; sv.z = silv[2]; sv.w = silv[3];
            *(u16x4*)(As + row * LDK + 80 + fq * 4) = sv;
        }
        {
            const int orow = tid >> 1;
            const int half = tid & 1;
            const float* sbase = SW + (size_t)(n0 + orow) * (KIN * 5) + i0 * 5 + half * 40;
            unsigned short* brow = Bs + orow * LDK + half * 40;
            #pragma unroll
            for (int p = 0; p < 10; ++p) {
                const f32x4 wv = *(const f32x4*)(sbase + p * 4);
                u16x4 v;
                v.x = f2bf(wv.x); v.y = f2bf(wv.y);
                v.z = f2bf(wv.z); v.w = f2bf(wv.w);
                *(u16x4*)(brow + p * 4) = v;
            }
        }
        #pragma unroll
        for (int s = 0; s < 2; ++s) {
            const int slot = tid + s * 256;
            const int row  = slot >> 2;
            const int fq   = slot & 3;
            const f32x4 wv = *(const f32x4*)(BW + (size_t)(n0 + row) * KIN + i0 + fq * 4);
            u16x4 v;
            v.x = f2bf(wv.x); v.y = f2bf(wv.y);
            v.z = f2bf(wv.z); v.w = f2bf(wv.w);
            *(u16x4*)(Bs + row * LDK + 80 + fq * 4) = v;
        }
        __syncthreads();
        #pragma unroll
        for (int ks = 0; ks < 3; ++ks) {
            bf16x8 af[4], bfr[4];
            #pragma unroll
            for (int mi = 0; mi < 4; ++mi)
                af[mi] = *(const bf16x8*)(As + (wm + mi * 16 + r) * LDK + ks * 32 + quad * 8);
            #pragma unroll
            for (int ni = 0; ni < 4; ++ni)
                bfr[ni] = *(const bf16x8*)(Bs + (wn + ni * 16 + r) * LDK + ks * 32 + quad * 8);
            #pragma unroll
            for (int mi = 0; mi < 4; ++mi)
                #pragma unroll
                for (int ni = 0; ni < 4; ++ni)
                    acc[mi][ni] = __builtin_amdgcn_mfma_f32_16x16x32_bf16(
                        af[mi], bfr[ni], acc[mi][ni], 0, 0, 0);
        }
    }
    #pragma unroll
    for (int mi = 0; mi < 4; ++mi) {
        #pragma unroll
        for (int ni = 0; ni < 4; ++ni) {
            const int col  = n0 + wn + ni * 16 + r;
            const int rowb = m0 + wm + mi * 16 + quad * 4;
            #pragma unroll
            for (int reg = 0; reg < 4; ++reg)
                OUT[(size_t)(rowb + reg) * NOUT + col] = acc[mi][ni][reg];
        }
    }
}

extern "C" void kernel_launch(void* const* d_in, const int* in_sizes, int n_in,
                              void* d_out, int out_size, void* d_ws, size_t ws_size,
                              hipStream_t stream) {
    const float* X  = (const float*)d_in[0];
    const float* BW = (const float*)d_in[1];
    const float* SW = (const float*)d_in[2];
    float* OUT = (float*)d_out;

    const size_t nA = (size_t)BATCH * KEXP;          // 201,326,592 elems
    const size_t nW = (size_t)NOUT * KEXP;           //  25,165,824 elems
    const size_t ws_need = (nA + nW) * sizeof(__bf16);   // 452,984,832 B

    if (ws_size >= ws_need) {
        __bf16* Aexp = (__bf16*)d_ws;
        __bf16* Wexp = Aexp + nA;
        expand_a<<<dim3(BATCH * 512 / 256), dim3(256), 0, stream>>>(X, Aexp);
        expand_w<<<dim3(NOUT * 512 / 256), dim3(256), 0, stream>>>(BW, SW, Wexp);
        gemm8<<<dim3(512), dim3(512), 0, stream>>>(Aexp, Wexp, OUT);
    } else {
        kan_fused<<<dim3(128 * 16), dim3(256), 0, stream>>>(X, BW, SW, OUT);
    }
}

// Round 3
// 970.368 us; speedup vs baseline: 1.4626x; 1.0262x over previous
//
#include <hip/hip_runtime.h>
#include <hip/hip_bf16.h>
#include <cstdint>
#include <cstddef>

// out[b,o] = sum_i silu(x[b,i])*BW[o,i] + sum_{i,c} exp(-5*(x[b,i]-g_c)^2)*SW[o,i,c]
// Round 6: GEMM (8-phase 256^2 + T1 swizzle, 1186 TF, MfmaUtil 56%) untouched.
// Expansion kernels rewritten: total-time minus GEMM was ~300 us vs ~115 us ideal.
//   (a) writes were 3x16B per lane at 48B lane stride (uncoalesced, 403 MB) ->
//       now staged through a 24 KB LDS row buffer and written 16B/lane contiguous.
//   (b) RBF basis via ratio recurrence: basis_{c+1} = basis_c * exp(5x) * k_c,
//       k_c = exp(-5*g_c - 1.25) compile-time consts -> 2 exps instead of 5.
//       Rel err ~1e-6 (invisible under bf16); underflow corners (|x|>3.2) give 0
//       where the true value is < 3e-11 -- negligible at the 0.0625 absmax scale.

#define KIN 2048
#define NOUT 2048
#define BATCH 16384
#define KEXP 12288          // 2048 * 6
#define NKT 192             // KEXP / 64

typedef __bf16 bf16x8 __attribute__((ext_vector_type(8)));
typedef float f32x4 __attribute__((ext_vector_type(4)));
typedef unsigned short u16x4 __attribute__((ext_vector_type(4)));

__device__ __forceinline__ unsigned short f2bf(float f) {
    union { float f; uint32_t u; } v; v.f = f;
    return (unsigned short)((v.u + 0x7FFFu + ((v.u >> 16) & 1u)) >> 16);
}

__device__ __forceinline__ void load_lds16(const void* gptr, void* lptr) {
    __builtin_amdgcn_global_load_lds(
        (const __attribute__((address_space(1))) unsigned int*)gptr,
        (__attribute__((address_space(3))) unsigned int*)lptr,
        16, 0, 0);
}

// ---------------- expansion: x -> Aexp (bf16, k = i*6 + j), one row/block ------
// Reads: 2x f32x4 per thread, 16B/lane contiguous. Compute: 2 exps for the 5-pt
// RBF chain + silu. Stage 24 KB row in LDS, write out 6x 16B/lane contiguous.
__global__ __launch_bounds__(256)
void expand_a(const float* __restrict__ X, __bf16* __restrict__ Aexp)
{
    __shared__ __align__(16) __bf16 rowbuf[KEXP];   // 24 KB
    const int row = blockIdx.x;
    const int tid = threadIdx.x;
    const float* xrow = X + (size_t)row * KIN;

    // k_c = exp(-5*g_c - 1.25), g_c = -1 + 0.5c
    const float K0 = 42.521082000062783f;   // exp(3.75)
    const float K1 = 3.4903429574597902f;   // exp(1.25)
    const float K2 = 0.2865047968601901f;   // exp(-1.25)
    const float K3 = 0.023517745856009107f; // exp(-3.75)

    #pragma unroll
    for (int s = 0; s < 2; ++s) {
        const f32x4 xv = *(const f32x4*)(xrow + (s * 256 + tid) * 4);
        float o[24];
        #pragma unroll
        for (int e = 0; e < 4; ++e) {
            const float xf = xv[e];
            const float d0 = xf + 1.0f;
            float b = __expf(-5.0f * d0 * d0);     // basis at g=-1
            const float s5 = __expf(5.0f * xf);    // ratio driver
            o[e * 6 + 0] = b;
            b *= s5 * K0; o[e * 6 + 1] = b;
            b *= s5 * K1; o[e * 6 + 2] = b;
            b *= s5 * K2; o[e * 6 + 3] = b;
            b *= s5 * K3; o[e * 6 + 4] = b;
            o[e * 6 + 5] = xf / (1.0f + __expf(-xf));
        }
        __bf16* dst = rowbuf + (s * 1024 + tid * 4) * 6;
        #pragma unroll
        for (int q = 0; q < 3; ++q) {
            bf16x8 v;
            #pragma unroll
            for (int t = 0; t < 8; ++t) v[t] = (__bf16)o[q * 8 + t];
            *(bf16x8*)(dst + q * 8) = v;
        }
    }
    __syncthreads();
    bf16x8* out = (bf16x8*)(Aexp + (size_t)row * KEXP);
    const bf16x8* lsrc = (const bf16x8*)rowbuf;
    #pragma unroll
    for (int t = 0; t < 6; ++t)
        out[tid + t * 256] = lsrc[tid + t * 256];
}

// ---------------- expansion: BW/SW -> Wexp (bf16, same k order), one row/block --
__global__ __launch_bounds__(256)
void expand_w(const float* __restrict__ BW, const float* __restrict__ SW,
              __bf16* __restrict__ Wexp)
{
    __shared__ __align__(16) __bf16 rowbuf[KEXP];   // 24 KB
    const int orow = blockIdx.x;
    const int tid  = threadIdx.x;

    #pragma unroll
    for (int s = 0; s < 2; ++s) {
        const int i0 = s * 1024 + tid * 4;
        const float* sb = SW + ((size_t)orow * KIN + i0) * 5;   // 20 contiguous floats
        const f32x4 bw = *(const f32x4*)(BW + (size_t)orow * KIN + i0);
        float sw[20];
        #pragma unroll
        for (int q = 0; q < 5; ++q) {
            const f32x4 v = *(const f32x4*)(sb + q * 4);
            sw[q * 4 + 0] = v.x; sw[q * 4 + 1] = v.y;
            sw[q * 4 + 2] = v.z; sw[q * 4 + 3] = v.w;
        }
        __bf16* dst = rowbuf + (size_t)i0 * 6;
        #pragma unroll
        for (int q = 0; q < 3; ++q) {
            bf16x8 v;
            #pragma unroll
            for (int t = 0; t < 8; ++t) {
                const int e = (q * 8 + t) / 6;
                const int c = (q * 8 + t) % 6;
                v[t] = (c < 5) ? (__bf16)sw[e * 5 + c] : (__bf16)bw[e];
            }
            *(bf16x8*)(dst + q * 8) = v;
        }
    }
    __syncthreads();
    bf16x8* out = (bf16x8*)(Wexp + (size_t)orow * KEXP);
    const bf16x8* lsrc = (const bf16x8*)rowbuf;
    #pragma unroll
    for (int t = 0; t < 6; ++t)
        out[tid + t * 256] = lsrc[tid + t * 256];
}

// ---------------- 256x256 8-phase GEMM: OUT[16384][2048] = Aexp * Wexp^T --------
// Per iteration: 2 K-tiles (BK=64 each), 8 phases. Phase = {ds_read subtile,
// stage 1 k-half slot (2 x global_load_lds 16B), s_barrier, setprio(1), 16 MFMA,
// setprio(0), s_barrier}. vmcnt(6) only at phases 4 and 8.
//
// T1: blockIdx remapped (bid%8 = XCD under round-robin dispatch) so XCD k owns
// m-tiles [8k, 8k+8) x all 8 n-tiles. 512 % 8 == 0 -> simple form is bijective.
// Measured: FETCH_SIZE 2.18 GB -> 600 MB, MfmaUtil 56%, bank conflicts 0.
__global__ __launch_bounds__(512, 2)
void gemm8(const __bf16* __restrict__ A, const __bf16* __restrict__ W,
           float* __restrict__ OUT)
{
    __shared__ __align__(16) __bf16 LDS[65536];   // 128 KiB
    __bf16* LA = LDS;              // [2buf][2kh][8192 elems]
    __bf16* LB = LDS + 32768;

    const int tid  = threadIdx.x;
    const int lane = tid & 63;
    const int wave = tid >> 6;     // 0..7
    const int r    = lane & 15;
    const int quad = lane >> 4;
    const int wm   = wave >> 2;    // 0..1  (M)
    const int wn   = wave & 3;     // 0..3  (N)

    // T1 XCD-aware bijective swizzle: 512 blocks, 8 XCDs, chunk = 64.
    const int bid0 = blockIdx.x;
    const int bid  = (bid0 & 7) * 64 + (bid0 >> 3);
    const int mt  = bid >> 3;      // 64 m-tiles
    const int nt  = bid & 7;       // 8 n-tiles
    const int m0  = mt * 256;
    const int n0  = nt * 256;

    // ---- staging source addresses (per-lane, pre-swizzled) ----
    const int c0   = tid;                          // slot chunk ids 0..511
    const int c1   = tid + 512;                    // 512..1023
    const int row0 = c0 >> 2, row1 = c1 >> 2;      // slot rows 0..255
    const int j0   = (c0 & 3) ^ ((c0 >> 3) & 3);   // logical chunk for phys slot
    const int j1   = (c1 & 3) ^ ((c1 >> 3) & 3);
    const __bf16* srcA0 = A + (size_t)(m0 + row0) * KEXP + j0 * 8;
    const __bf16* srcA1 = A + (size_t)(m0 + row1) * KEXP + j1 * 8;
    const __bf16* srcB0 = W + (size_t)(n0 + row0) * KEXP + j0 * 8;
    const __bf16* srcB1 = W + (size_t)(n0 + row1) * KEXP + j1 * 8;

    // LDS stage destinations: wave-uniform base; HW adds lane*16B.
    const int dst0 = wave * 512;          // issue s=0 (elems)
    const int dst1 = 4096 + wave * 512;   // issue s=1

    // ---- fragment read bases (swizzled) ----
    const int swz = (quad ^ ((r >> 1) & 3)) * 8;
    const __bf16* a_rd = LA + (wm * 128 + r) * 32 + swz;
    const __bf16* b_rd = LB + (wn * 64 + r) * 32 + swz;

    f32x4 acc[8][4];
    #pragma unroll
    for (int i = 0; i < 8; ++i)
        #pragma unroll
        for (int j = 0; j < 4; ++j)
            acc[i][j] = (f32x4){0.0f, 0.0f, 0.0f, 0.0f};

    bf16x8 af[4], bf[4];

#define BARX() asm volatile("s_barrier" ::: "memory")
#define VM6()  asm volatile("s_waitcnt vmcnt(6)" ::: "memory")

#define STAGE_A(buf, kh, kt) do { \
    const size_t ko = (size_t)(kt) * 64 + (kh) * 32; \
    load_lds16(srcA0 + ko, LA + ((buf) * 2 + (kh)) * 8192 + dst0); \
    load_lds16(srcA1 + ko, LA + ((buf) * 2 + (kh)) * 8192 + dst1); } while (0)

#define STAGE_B(buf, kh, kt) do { \
    const size_t ko = (size_t)(kt) * 64 + (kh) * 32; \
    load_lds16(srcB0 + ko, LB + ((buf) * 2 + (kh)) * 8192 + dst0); \
    load_lds16(srcB1 + ko, LB + ((buf) * 2 + (kh)) * 8192 + dst1); } while (0)

#define READ_A(buf, ks, a) do { \
    const __bf16* p_ = a_rd + ((buf) * 2 + (ks)) * 8192 + (a) * 2048; \
    af[0] = *(const bf16x8*)(p_); \
    af[1] = *(const bf16x8*)(p_ + 512); \
    af[2] = *(const bf16x8*)(p_ + 1024); \
    af[3] = *(const bf16x8*)(p_ + 1536); } while (0)

#define READ_B(buf, ks) do { \
    const __bf16* p_ = b_rd + ((buf) * 2 + (ks)) * 8192; \
    bf[0] = *(const bf16x8*)(p_); \
    bf[1] = *(const bf16x8*)(p_ + 512); \
    bf[2] = *(const bf16x8*)(p_ + 1024); \
    bf[3] = *(const bf16x8*)(p_ + 1536); } while (0)

#define MFMA_Q(a) do { \
    __builtin_amdgcn_s_setprio(1); \
    _Pragma("unroll") \
    for (int mi_ = 0; mi_ < 4; ++mi_) { \
        _Pragma("unroll") \
        for (int nj_ = 0; nj_ < 4; ++nj_) \
            acc[(a) * 4 + mi_][nj_] = __builtin_amdgcn_mfma_f32_16x16x32_bf16( \
                af[mi_], bf[nj_], acc[(a) * 4 + mi_][nj_], 0, 0, 0); \
    } \
    __builtin_amdgcn_s_setprio(0); } while (0)

    // ---- prologue: K-tile 0 full (buf0) + 3 of K-tile 1 (buf1) = 14 loads ----
    STAGE_B(0, 0, 0); STAGE_A(0, 0, 0); STAGE_B(0, 1, 0); STAGE_A(0, 1, 0);
    STAGE_B(1, 0, 1); STAGE_A(1, 0, 1); STAGE_B(1, 1, 1);
    VM6();            // completes the 4 buf0 slots; leaves buf1's 3 in flight
    BARX();

    // ---- main loop: 96 iterations x 2 K-tiles ----
    for (int t = 0; t < 96; ++t) {
        const int kt1 = 2 * t + 1;
        const int sA  = (2 * t + 2 < NKT) ? 2 * t + 2 : NKT - 1;  // clamp: staged-
        const int sB  = (2 * t + 3 < NKT) ? 2 * t + 3 : NKT - 1;  // never-read tail
        // p1: quad (a=0, ks=0) of buf0; stage A[buf1,khi] <- kt1 (needed p7/p8)
        READ_A(0, 0, 0); READ_B(0, 0);
        STAGE_A(1, 1, kt1);
        BARX(); MFMA_Q(0); BARX();
        // p2: (a=1, ks=0), B ks0 reused from regs; stage B[buf0,klo] <- kt+2
        READ_A(0, 0, 1);
        STAGE_B(0, 0, sA);
        BARX(); MFMA_Q(1); BARX();
        // p3: (a=1, ks=1); stage A[buf0,klo]
        READ_A(0, 1, 1); READ_B(0, 1);
        STAGE_A(0, 0, sA);
        BARX(); MFMA_Q(1); BARX();
        // p4: (a=0, ks=1); stage B[buf0,khi]; counted vmcnt
        READ_A(0, 1, 0);
        STAGE_B(0, 1, sA);
        VM6();
        BARX(); MFMA_Q(0); BARX();
        // p5: buf1 (a=0, ks=0); stage A[buf0,khi]
        READ_A(1, 0, 0); READ_B(1, 0);
        STAGE_A(0, 1, sA);
        BARX(); MFMA_Q(0); BARX();
        // p6: (a=1, ks=0); stage B[buf1,klo] <- kt+3
        READ_A(1, 0, 1);
        STAGE_B(1, 0, sB);
        BARX(); MFMA_Q(1); BARX();
        // p7: (a=1, ks=1); stage A[buf1,klo]
        READ_A(1, 1, 1); READ_B(1, 1);
        STAGE_A(1, 0, sB);
        BARX(); MFMA_Q(1); BARX();
        // p8: (a=0, ks=1); stage B[buf1,khi]; counted vmcnt
        READ_A(1, 1, 0);
        STAGE_B(1, 1, sB);
        VM6();
        BARX(); MFMA_Q(0); BARX();
    }

    // ---- epilogue: C/D layout col = lane&15, row = quad*4 + reg ----
    #pragma unroll
    for (int fi = 0; fi < 8; ++fi) {
        #pragma unroll
        for (int nj = 0; nj < 4; ++nj) {
            const int col  = n0 + wn * 64 + nj * 16 + r;
            const int rowb = m0 + wm * 128 + fi * 16 + quad * 4;
            #pragma unroll
            for (int reg = 0; reg < 4; ++reg)
                OUT[(size_t)(rowb + reg) * NOUT + col] = acc[fi][nj][reg];
        }
    }
#undef BARX
#undef VM6
#undef STAGE_A
#undef STAGE_B
#undef READ_A
#undef READ_B
#undef MFMA_Q
}

// ---------------- fallback: validated round-2 fused kernel ----------------
#define BM 128
#define BN 128
#define NF 16
#define BK 96
#define LDK 104

__global__ __launch_bounds__(256)
void kan_fused(const float* __restrict__ X, const float* __restrict__ BW,
               const float* __restrict__ SW, float* __restrict__ OUT)
{
    __shared__ __align__(16) unsigned short As[BM * LDK];
    __shared__ __align__(16) unsigned short Bs[BN * LDK];

    const int tid  = threadIdx.x;
    const int lane = tid & 63;
    const int wave = tid >> 6;
    const int mt = blockIdx.x >> 4;
    const int nt = blockIdx.x & 15;
    const int m0 = mt * BM;
    const int n0 = nt * BN;
    const int r    = lane & 15;
    const int quad = lane >> 4;
    const int wm = (wave & 1) * 64;
    const int wn = (wave >> 1) * 64;

    f32x4 acc[4][4];
    #pragma unroll
    for (int i = 0; i < 4; ++i)
        #pragma unroll
        for (int j = 0; j < 4; ++j)
            acc[i][j] = (f32x4){0.0f, 0.0f, 0.0f, 0.0f};

    for (int it = 0; it < KIN / NF; ++it) {
        const int i0 = it * NF;
        __syncthreads();
        #pragma unroll
        for (int s = 0; s < 2; ++s) {
            const int slot = tid + s * 256;
            const int row  = slot >> 2;
            const int fq   = slot & 3;
            const f32x4 xv = *(const f32x4*)(X + (size_t)(m0 + row) * KIN + i0 + fq * 4);
            unsigned short basv[20];
            unsigned short silv[4];
            #pragma unroll
            for (int e = 0; e < 4; ++e) {
                const float xf = xv[e];
                silv[e] = f2bf(xf / (1.0f + __expf(-xf)));
                #pragma unroll
                for (int c = 0; c < 5; ++c) {
                    const float d = xf - (-1.0f + 0.5f * (float)c);
                    basv[e * 5 + c] = f2bf(__expf(-5.0f * d * d));
                }
            }
            unsigned short* dst = As + row * LDK + fq * 20;
            #pragma unroll
            for (int q = 0; q < 5; ++q) {
                u16x4 v;
                v.x = basv[q * 4 + 0]; v.y = basv[q * 4 + 1];
                v.z = basv[q * 4 + 2]; v.w = basv[q * 4 + 3];
                *(u16x4*)(dst + q * 4) = v;
            }
            u16x4 sv;
            sv.x = silv[0]; sv.y = silv[1]; sv.z = silv[2]; sv.w = silv[3];
            *(u16x4*)(As + row * LDK + 80 + fq * 4) = sv;
        }
        {
            const int orow = tid >> 1;
            const int half = tid & 1;
            const float* sbase = SW + (size_t)(n0 + orow) * (KIN * 5) + i0 * 5 + half * 40;
            unsigned short* brow = Bs + orow * LDK + half * 40;
            #pragma unroll
            for (int p = 0; p < 10; ++p) {
                const f32x4 wv = *(const f32x4*)(sbase + p * 4);
                u16x4 v;
                v.x = f2bf(wv.x); v.y = f2bf(wv.y);
                v.z = f2bf(wv.z); v.w = f2bf(wv.w);
                *(u16x4*)(brow + p * 4) = v;
            }
        }
        #pragma unroll
        for (int s = 0; s < 2; ++s) {
            const int slot = tid + s * 256;
            const int row  = slot >> 2;
            const int fq   = slot & 3;
            const f32x4 wv = *(const f32x4*)(BW + (size_t)(n0 + row) * KIN + i0 + fq * 4);
            u16x4 v;
            v.x = f2bf(wv.x); v.y = f2bf(wv.y);
            v.z = f2bf(wv.z); v.w = f2bf(wv.w);
            *(u16x4*)(Bs + row * LDK + 80 + fq * 4) = v;
        }
        __syncthreads();
        #pragma unroll
        for (int ks = 0; ks < 3; ++ks) {
            bf16x8 af[4], bfr[4];
            #pragma unroll
            for (int mi = 0; mi < 4; ++mi)
                af[mi] = *(const bf16x8*)(As + (wm + mi * 16 + r) * LDK + ks * 32 + quad * 8);
            #pragma unroll
            for (int ni = 0; ni < 4; ++ni)
                bfr[ni] = *(const bf16x8*)(Bs + (wn + ni * 16 + r) * LDK + ks * 32 + quad * 8);
            #pragma unroll
            for (int mi = 0; mi < 4; ++mi)
                #pragma unroll
                for (int ni = 0; ni < 4; ++ni)
                    acc[mi][ni] = __builtin_amdgcn_mfma_f32_16x16x32_bf16(
                        af[mi], bfr[ni], acc[mi][ni], 0, 0, 0);
        }
    }
    #pragma unroll
    for (int mi = 0; mi < 4; ++mi) {
        #pragma unroll
        for (int ni = 0; ni < 4; ++ni) {
            const int col  = n0 + wn + ni * 16 + r;
            const int rowb = m0 + wm + mi * 16 + quad * 4;
            #pragma unroll
            for (int reg = 0; reg < 4; ++reg)
                OUT[(size_t)(rowb + reg) * NOUT + col] = acc[mi][ni][reg];
        }
    }
}

extern "C" void kernel_launch(void* const* d_in, const int* in_sizes, int n_in,
                              void* d_out, int out_size, void* d_ws, size_t ws_size,
                              hipStream_t stream) {
    const float* X  = (const float*)d_in[0];
    const float* BW = (const float*)d_in[1];
    const float* SW = (const float*)d_in[2];
    float* OUT = (float*)d_out;

    const size_t nA = (size_t)BATCH * KEXP;          // 201,326,592 elems
    const size_t nW = (size_t)NOUT * KEXP;           //  25,165,824 elems
    const size_t ws_need = (nA + nW) * sizeof(__bf16);   // 452,984,832 B

    if (ws_size >= ws_need) {
        __bf16* Aexp = (__bf16*)d_ws;
        __bf16* Wexp = Aexp + nA;
        expand_a<<<dim3(BATCH), dim3(256), 0, stream>>>(X, Aexp);
        expand_w<<<dim3(NOUT), dim3(256), 0, stream>>>(BW, SW, Wexp);
        gemm8<<<dim3(512), dim3(512), 0, stream>>>(Aexp, Wexp, OUT);
    } else {
        kan_fused<<<dim3(128 * 16), dim3(256), 0, stream>>>(X, BW, SW, OUT);
    }
}